// Round 2
// baseline (517.935 us; speedup 1.0000x reference)
//
#include <hip/hip_runtime.h>

// Fused Canny-style edge pipeline, 1x3x4096x4096 fp32 -> 1x4096x4096 fp32.
// R2: 32x32 tile, group-of-4-column vectorization, 22.8 KB LDS (6-7 blocks/CU).
// R3: Stage-D wave-level early-out on the [6,50] magnitude band + guarded
//     comparison-based orientation with bit-exact atan2f fallback.
// R4: cross-channel sums (s_bs, s_mg) accumulate in REGISTERS (thread->task
//     map is channel-invariant), written to LDS once at ch2; Stage A(ch+1)
//     global loads prefetched at start of B(ch) and its LDS write fused into
//     the C(ch) phase (barriers 9->7, HBM latency hidden under B+C); whole
//     pipeline templated on INTERIOR so 97% of blocks compile out all bounds
//     checks. Arithmetic order unchanged -> bit-identical output.

#define IMG_H 4096
#define IMG_W 4096

constexpr int TW = 32, TH = 32;
constexpr int HBH = 40, HBW = 40;  // hblur:   (r,c) -> abs (Y0-4+r, X0-2+c)
constexpr int BH  = 36, BW  = 40;  // blurred: (r,c) -> abs (Y0-2+r, X0-2+c)
constexpr int MH  = 34, MW  = 36;  // gradmag: (r,c) -> abs (Y0-1+r, X0-1+c)

template<bool INTERIOR>
__device__ __forceinline__ void pipeline(
    const float* __restrict__ img,
    float g0, float g1, float g2, float g3, float g4,
    int X0, int Y0, int tid,
    float* __restrict__ s_hb, float* __restrict__ s_bl,
    float* __restrict__ s_bs, float* __restrict__ s_mg,
    float* __restrict__ out) {

  // ---- fixed thread->task maps (channel-invariant) ----
  const int rA0 = tid / 10, cA0 = (tid - rA0 * 10) * 4;   // A/B: 40x10 groups
  const int jA1 = tid + 256;
  const int rA1 = jA1 / 10, cA1 = (jA1 - rA1 * 10) * 4;
  const bool hasA1 = (tid < 144);                          // 400 tasks
  const bool hasB1 = (tid < 104);                          // 360 tasks
  const int rC0 = tid / 9,  cC0 = (tid - rC0 * 9) * 4;     // C: 34x9 groups
  const int jC1 = tid + 256;
  const int rC1 = jC1 / 9,  cC1 = (jC1 - rC1 * 9) * 4;
  const bool hasC1 = (tid < 50);                           // 306 tasks

  float4 pa0, pb0, pa1, pb1;          // Stage-A prefetch registers
  float4 bsA0, bsA1, mgA0, mgA1;      // cross-channel accumulators

  // ---- Stage A prefetch: issue global loads (regs only, no LDS) ----
  auto prefA = [&](int ch) {
    const float* im = img + (size_t)ch * ((size_t)IMG_H * IMG_W);
    if (INTERIOR) {
      const float* r0 = im + (size_t)(Y0 - 4 + rA0) * IMG_W + (X0 - 4 + cA0);
      pa0 = *(const float4*)r0;
      pb0 = *(const float4*)(r0 + 4);
      if (hasA1) {
        const float* r1 = im + (size_t)(Y0 - 4 + rA1) * IMG_W + (X0 - 4 + cA1);
        pa1 = *(const float4*)r1;
        pb1 = *(const float4*)(r1 + 4);
      }
    } else {
      auto ld = [&](int r, int c0, float4& va, float4& vb) {
        va = make_float4(0.f, 0.f, 0.f, 0.f);
        vb = make_float4(0.f, 0.f, 0.f, 0.f);
        int gy = Y0 - 4 + r;
        if ((unsigned)gy < IMG_H) {
          int cb = X0 - 4 + c0;
          const float* row = im + (size_t)gy * IMG_W;
          if (cb >= 0 && cb + 7 < IMG_W) {
            va = *(const float4*)(row + cb);
            vb = *(const float4*)(row + cb + 4);
          } else {
            float t[8];
#pragma unroll
            for (int u = 0; u < 8; ++u) {
              int x = cb + u;
              t[u] = ((unsigned)x < IMG_W) ? row[x] : 0.f;
            }
            va = make_float4(t[0], t[1], t[2], t[3]);
            vb = make_float4(t[4], t[5], t[6], t[7]);
          }
        }
      };
      ld(rA0, cA0, pa0, pb0);
      if (hasA1) ld(rA1, cA1, pa1, pb1);
    }
  };

  // ---- Stage A compute: horizontal gaussian from prefetch regs -> s_hb ----
  auto computeA = [&]() {
    auto h5 = [&](const float4& a, const float4& b) {
      float4 o;
      o.x = g0 * a.x + g1 * a.y + g2 * a.z + g3 * a.w + g4 * b.x;
      o.y = g0 * a.y + g1 * a.z + g2 * a.w + g3 * b.x + g4 * b.y;
      o.z = g0 * a.z + g1 * a.w + g2 * b.x + g3 * b.y + g4 * b.z;
      o.w = g0 * a.w + g1 * b.x + g2 * b.y + g3 * b.z + g4 * b.w;
      return o;
    };
    *(float4*)&s_hb[rA0 * HBW + cA0] = h5(pa0, pb0);
    if (hasA1) *(float4*)&s_hb[rA1 * HBW + cA1] = h5(pa1, pb1);
  };

  // ---- Stage B: vertical gaussian; s_bl store + register bs accumulate ----
  auto stageB = [&](int ch) {
    auto doB = [&](int r, int c0, float4& acc) {
      const float* p = &s_hb[r * HBW + c0];
      float4 a0 = *(const float4*)(p);
      float4 a1 = *(const float4*)(p + HBW);
      float4 a2 = *(const float4*)(p + 2 * HBW);
      float4 a3 = *(const float4*)(p + 3 * HBW);
      float4 a4 = *(const float4*)(p + 4 * HBW);
      float4 v;
      v.x = g0 * a0.x + g1 * a1.x + g2 * a2.x + g3 * a3.x + g4 * a4.x;
      v.y = g0 * a0.y + g1 * a1.y + g2 * a2.y + g3 * a3.y + g4 * a4.y;
      v.z = g0 * a0.z + g1 * a1.z + g2 * a2.z + g3 * a3.z + g4 * a4.z;
      v.w = g0 * a0.w + g1 * a1.w + g2 * a2.w + g3 * a3.w + g4 * a4.w;
      if (!INTERIOR) {
        int gy = Y0 - 2 + r;
        bool rok = (unsigned)gy < IMG_H;
        int gx0 = X0 - 2 + c0;
        v.x = (rok && (unsigned)(gx0    ) < IMG_W) ? v.x : 0.f;
        v.y = (rok && (unsigned)(gx0 + 1) < IMG_W) ? v.y : 0.f;
        v.z = (rok && (unsigned)(gx0 + 2) < IMG_W) ? v.z : 0.f;
        v.w = (rok && (unsigned)(gx0 + 3) < IMG_W) ? v.w : 0.f;
      }
      *(float4*)&s_bl[r * BW + c0] = v;
      if (ch == 0) {
        acc = v;
      } else {
        acc.x += v.x; acc.y += v.y; acc.z += v.z; acc.w += v.w;
      }
      if (ch == 2) *(float4*)&s_bs[r * BW + c0] = acc;
    };
    doB(rA0, cA0, bsA0);
    if (hasB1) doB(rA1, cA1, bsA1);
  };

  // ---- Stage C: Sobel + magnitude; register mg accumulate ----
  auto stageC = [&](int ch) {
    auto doC = [&](int r, int c0, float4& acc) {
      float w0[6], w1[6], w2[6];
      const float* p = &s_bl[r * BW + c0];
      { float4 a = *(const float4*)p;            float2 b = *(const float2*)(p + 4);
        w0[0]=a.x; w0[1]=a.y; w0[2]=a.z; w0[3]=a.w; w0[4]=b.x; w0[5]=b.y; }
      { float4 a = *(const float4*)(p + BW);     float2 b = *(const float2*)(p + BW + 4);
        w1[0]=a.x; w1[1]=a.y; w1[2]=a.z; w1[3]=a.w; w1[4]=b.x; w1[5]=b.y; }
      { float4 a = *(const float4*)(p + 2 * BW); float2 b = *(const float2*)(p + 2 * BW + 4);
        w2[0]=a.x; w2[1]=a.y; w2[2]=a.z; w2[3]=a.w; w2[4]=b.x; w2[5]=b.y; }
      float res[4];
#pragma unroll
      for (int e = 0; e < 4; ++e) {
        float gxv = w0[e] - w0[e + 2] + 2.f * w1[e] - 2.f * w1[e + 2] + w2[e] - w2[e + 2];
        float gyv = w0[e] + 2.f * w0[e + 1] + w0[e + 2] - w2[e] - 2.f * w2[e + 1] - w2[e + 2];
        float m = sqrtf(gxv * gxv + gyv * gyv + 1e-8f);
        if (!INTERIOR) {
          int gy = Y0 - 1 + r;
          int gx = X0 - 1 + c0 + e;
          m = ((unsigned)gy < IMG_H && (unsigned)gx < IMG_W) ? m : 0.f;
        }
        res[e] = m;
      }
      if (ch == 0) {
        acc = make_float4(res[0], res[1], res[2], res[3]);
      } else {
        acc.x += res[0]; acc.y += res[1]; acc.z += res[2]; acc.w += res[3];
      }
      if (ch == 2) *(float4*)&s_mg[r * MW + c0] = acc;
    };
    doC(rC0, cC0, mgA0);
    if (hasC1) doC(rC1, cC1, mgA1);
  };

  // ---- driver: prefetch A(ch+1) at start of B(ch); A-compute fused with C ----
  prefA(0);
  computeA();
  __syncthreads();
#pragma unroll
  for (int ch = 0; ch < 3; ++ch) {
    if (ch < 2) prefA(ch + 1);   // regs only; loads fly during B + C
    stageB(ch);
    __syncthreads();
    stageC(ch);
    if (ch < 2) computeA();      // s_hb free since B(ch) consumed it pre-bar
    __syncthreads();
  }

  // ---- Stage D: band early-out + orientation + NMS (unchanged from R3) ----
  {
    const int ty  = tid >> 3;         // 0..31
    const int tx0 = (tid & 7) << 2;   // 0..28 step 4
    const int row1 = (ty + 1) * MW;

    float4 q0 = *(const float4*)&s_mg[row1 + tx0];
    float4 q1 = *(const float4*)&s_mg[row1 + tx0 + 4];
    float mcs[4];
    mcs[0] = q0.y; mcs[1] = q0.z; mcs[2] = q0.w; mcs[3] = q1.x;

    bool band = false;
#pragma unroll
    for (int e = 0; e < 4; ++e)
      band = band || (mcs[e] >= 6.0f && mcs[e] <= 50.0f);

    float4 resv = make_float4(0.f, 0.f, 0.f, 0.f);
    if (__ballot(band) != 0ULL) {
      float w0[8], w1[8], w2[8];
#pragma unroll
      for (int rr = 0; rr < 3; ++rr) {
        float* w = (rr == 0) ? w0 : (rr == 1) ? w1 : w2;
        float4 p = *(const float4*)&s_bs[(ty + 1 + rr) * BW + tx0];
        float4 q = *(const float4*)&s_bs[(ty + 1 + rr) * BW + tx0 + 4];
        w[0]=p.x; w[1]=p.y; w[2]=p.z; w[3]=p.w; w[4]=q.x; w[5]=q.y; w[6]=q.z; w[7]=q.w;
      }
      const unsigned long long off_tbl = 0xDDDCDBFF23242501ULL;
      float res[4];
#pragma unroll
      for (int e = 0; e < 4; ++e) {
        int tx = tx0 + e;
        float b00 = w0[e + 1], b01 = w0[e + 2], b02 = w0[e + 3];
        float b10 = w1[e + 1],                  b12 = w1[e + 3];
        float b20 = w2[e + 1], b21 = w2[e + 2], b22 = w2[e + 3];
        float gxs = b00 - b02 + 2.f * b10 - 2.f * b12 + b20 - b22;
        float gys = b00 + 2.f * b01 + b02 - b20 - 2.f * b21 - b22;
        float ax = fabsf(gxs), ay = fabsf(gys);
        float f1 = ay - 0.41421356f * ax;
        float f2 = ay - 2.4142137f * ax;
        int off;
        if (fminf(fabsf(f1), fabsf(f2)) < 1e-4f * (ax + ay)) {
          float ori = atan2f(gys, gxs) * 57.295827908797776f + 180.0f;  // 180/3.14159
          int k = (int)rintf(ori / 45.0f);   // round-half-even like jnp.round
          int ip = k & 7;
          off = (int)(signed char)(off_tbl >> (ip * 8));
        } else {
          off = (f1 <= 0.f) ? 1
              : (f2 >= 0.f) ? MW
              : (((__float_as_uint(gxs) ^ __float_as_uint(gys)) >> 31) ? (MW - 1)
                                                                       : (MW + 1));
        }
        int ctr = row1 + (tx + 1);
        float mc  = mcs[e];
        float csp = mc - s_mg[ctr + off];
        float csn = mc - s_mg[ctr - off];
        bool is_max = fminf(csp, csn) > 0.0f;
        bool keep = is_max && (mc >= 6.0f) && (mc <= 50.0f);
        res[e] = keep ? 1.0f : 0.0f;
      }
      resv = make_float4(res[0], res[1], res[2], res[3]);
    }
    *(float4*)&out[(size_t)(Y0 + ty) * IMG_W + (X0 + tx0)] = resv;
  }
}

__global__ __launch_bounds__(256, 6)
void canny_fused(const float* __restrict__ img,
                 const float* __restrict__ gauss,
                 float* __restrict__ out) {
  __shared__ float s_hb[HBH * HBW];  // per-channel horizontal blur (transient)
  __shared__ float s_bl[BH * BW];    // per-channel blurred (transient)
  __shared__ float s_bs[BH * BW];    // sum over channels of blurred (ch2 write)
  __shared__ float s_mg[MH * MW];    // grad_mag summed over channels (ch2 write)

  const int tid = threadIdx.x;
  const int X0 = blockIdx.x * TW;
  const int Y0 = blockIdx.y * TH;
  const float g0 = gauss[0], g1 = gauss[1], g2 = gauss[2],
              g3 = gauss[3], g4 = gauss[4];

  // Stage A touches rows Y0-4..Y0+35, cols X0-4..X0+39 -> interior iff
  // bx in [1,126] and by in [1,126] (97% of blocks).
  const bool interior = (blockIdx.x >= 1) && (blockIdx.x <= 126) &&
                        (blockIdx.y >= 1) && (blockIdx.y <= 126);
  if (interior)
    pipeline<true >(img, g0, g1, g2, g3, g4, X0, Y0, tid, s_hb, s_bl, s_bs, s_mg, out);
  else
    pipeline<false>(img, g0, g1, g2, g3, g4, X0, Y0, tid, s_hb, s_bl, s_bs, s_mg, out);
}

extern "C" void kernel_launch(void* const* d_in, const int* in_sizes, int n_in,
                              void* d_out, int out_size, void* d_ws, size_t ws_size,
                              hipStream_t stream) {
  const float* img   = (const float*)d_in[0];
  const float* gauss = (const float*)d_in[1];
  float* out = (float*)d_out;
  dim3 grid(IMG_W / TW, IMG_H / TH);
  canny_fused<<<grid, 256, 0, stream>>>(img, gauss, out);
}

// Round 3
// 341.595 us; speedup vs baseline: 1.5162x; 1.5162x over previous
//
#include <hip/hip_runtime.h>

// Fused Canny-style edge pipeline, 1x3x4096x4096 fp32 -> 1x4096x4096 fp32.
// R2: 32x32 tile, group-of-4-column vectorization, 22.8 KB LDS (6-7 blocks/CU).
// R3: Stage-D wave-level early-out on the [6,50] magnitude band + guarded
//     comparison-based orientation with bit-exact atan2f fallback. (146 us)
// R4: register pipelining + accumulators -> VGPR pressure -> scratch spills
//     (WRITE_SIZE 65KB -> 554MB). REVERTED.
// R5: R3 structure exactly, plus interior-block template specialization:
//     97% of blocks (bx,by in [1,126]) compile out all bounds checks in
//     stages A-C. No extra live registers; arithmetic order unchanged.

#define IMG_H 4096
#define IMG_W 4096

constexpr int TW = 32, TH = 32;
constexpr int HBH = 40, HBW = 40;  // hblur:   (r,c) -> abs (Y0-4+r, X0-2+c)
constexpr int BH  = 36, BW  = 40;  // blurred: (r,c) -> abs (Y0-2+r, X0-2+c)
constexpr int MH  = 34, MW  = 36;  // gradmag: (r,c) -> abs (Y0-1+r, X0-1+c)

template<bool INTERIOR>
__device__ __forceinline__ void pipeline(
    const float* __restrict__ img,
    float g0, float g1, float g2, float g3, float g4,
    int X0, int Y0, int tid,
    float* __restrict__ s_hb, float* __restrict__ s_bl,
    float* __restrict__ s_bs, float* __restrict__ s_mg,
    float* __restrict__ out) {

  for (int ch = 0; ch < 3; ++ch) {
    const float* im = img + (size_t)ch * ((size_t)IMG_H * IMG_W);

    // ---- Stage A: horizontal gaussian, 4 cols per task (40 rows x 10 groups).
    for (int j = tid; j < HBH * 10; j += 256) {
      int r = j / 10, g = j - r * 10;
      int c0 = g * 4;
      int gy = Y0 - 4 + r;
      float4 o;
      if (INTERIOR) {
        const float* row = im + (size_t)gy * IMG_W + (X0 - 4 + c0);
        float4 va = *(const float4*)(row);
        float4 vb = *(const float4*)(row + 4);
        o.x = g0 * va.x + g1 * va.y + g2 * va.z + g3 * va.w + g4 * vb.x;
        o.y = g0 * va.y + g1 * va.z + g2 * va.w + g3 * vb.x + g4 * vb.y;
        o.z = g0 * va.z + g1 * va.w + g2 * vb.x + g3 * vb.y + g4 * vb.z;
        o.w = g0 * va.w + g1 * vb.x + g2 * vb.y + g3 * vb.z + g4 * vb.w;
      } else if ((unsigned)gy < IMG_H) {
        int cb = X0 - 4 + c0;
        const float* row = im + (size_t)gy * IMG_W;
        float a0, a1, a2, a3, a4, a5, a6, a7;
        if (cb >= 0 && cb + 7 < IMG_W) {
          float4 va = *(const float4*)(row + cb);
          float4 vb = *(const float4*)(row + cb + 4);
          a0 = va.x; a1 = va.y; a2 = va.z; a3 = va.w;
          a4 = vb.x; a5 = vb.y; a6 = vb.z; a7 = vb.w;
        } else {
          float t[8];
#pragma unroll
          for (int u = 0; u < 8; ++u) {
            int x = cb + u;
            t[u] = ((unsigned)x < IMG_W) ? row[x] : 0.f;
          }
          a0 = t[0]; a1 = t[1]; a2 = t[2]; a3 = t[3];
          a4 = t[4]; a5 = t[5]; a6 = t[6]; a7 = t[7];
        }
        o.x = g0 * a0 + g1 * a1 + g2 * a2 + g3 * a3 + g4 * a4;
        o.y = g0 * a1 + g1 * a2 + g2 * a3 + g3 * a4 + g4 * a5;
        o.z = g0 * a2 + g1 * a3 + g2 * a4 + g3 * a5 + g4 * a6;
        o.w = g0 * a3 + g1 * a4 + g2 * a5 + g3 * a6 + g4 * a7;
      } else {
        o = make_float4(0.f, 0.f, 0.f, 0.f);
      }
      *(float4*)&s_hb[r * HBW + c0] = o;
    }
    __syncthreads();

    // ---- Stage B: vertical gaussian (36 rows x 10 groups).
    for (int j = tid; j < BH * 10; j += 256) {
      int r = j / 10, g = j - r * 10;
      int c0 = g * 4;
      const float* p = &s_hb[r * HBW + c0];
      float4 a0 = *(const float4*)(p);
      float4 a1 = *(const float4*)(p + HBW);
      float4 a2 = *(const float4*)(p + 2 * HBW);
      float4 a3 = *(const float4*)(p + 3 * HBW);
      float4 a4 = *(const float4*)(p + 4 * HBW);
      float4 v;
      v.x = g0 * a0.x + g1 * a1.x + g2 * a2.x + g3 * a3.x + g4 * a4.x;
      v.y = g0 * a0.y + g1 * a1.y + g2 * a2.y + g3 * a3.y + g4 * a4.y;
      v.z = g0 * a0.z + g1 * a1.z + g2 * a2.z + g3 * a3.z + g4 * a4.z;
      v.w = g0 * a0.w + g1 * a1.w + g2 * a2.w + g3 * a3.w + g4 * a4.w;
      if (!INTERIOR) {
        int gy = Y0 - 2 + r;
        bool rok = (unsigned)gy < IMG_H;
        int gx0 = X0 - 2 + c0;
        v.x = (rok && (unsigned)(gx0    ) < IMG_W) ? v.x : 0.f;
        v.y = (rok && (unsigned)(gx0 + 1) < IMG_W) ? v.y : 0.f;
        v.z = (rok && (unsigned)(gx0 + 2) < IMG_W) ? v.z : 0.f;
        v.w = (rok && (unsigned)(gx0 + 3) < IMG_W) ? v.w : 0.f;
      }
      *(float4*)&s_bl[r * BW + c0] = v;
      float4* ps = (float4*)&s_bs[r * BW + c0];
      if (ch == 0) {
        *ps = v;
      } else {
        float4 s = *ps;
        s.x += v.x; s.y += v.y; s.z += v.z; s.w += v.w;
        *ps = s;
      }
    }
    __syncthreads();

    // ---- Stage C: Sobel + magnitude, accumulate (34 rows x 9 groups).
    for (int j = tid; j < MH * 9; j += 256) {
      int r = j / 9, g = j - r * 9;
      int c0 = g * 4;
      float w0[6], w1[6], w2[6];
      const float* p = &s_bl[r * BW + c0];
      { float4 a = *(const float4*)(p);          float2 b = *(const float2*)(p + 4);
        w0[0]=a.x; w0[1]=a.y; w0[2]=a.z; w0[3]=a.w; w0[4]=b.x; w0[5]=b.y; }
      { float4 a = *(const float4*)(p + BW);     float2 b = *(const float2*)(p + BW + 4);
        w1[0]=a.x; w1[1]=a.y; w1[2]=a.z; w1[3]=a.w; w1[4]=b.x; w1[5]=b.y; }
      { float4 a = *(const float4*)(p + 2 * BW); float2 b = *(const float2*)(p + 2 * BW + 4);
        w2[0]=a.x; w2[1]=a.y; w2[2]=a.z; w2[3]=a.w; w2[4]=b.x; w2[5]=b.y; }
      float res[4];
#pragma unroll
      for (int e = 0; e < 4; ++e) {
        float gxv = w0[e] - w0[e + 2] + 2.f * w1[e] - 2.f * w1[e + 2] + w2[e] - w2[e + 2];
        float gyv = w0[e] + 2.f * w0[e + 1] + w0[e + 2] - w2[e] - 2.f * w2[e + 1] - w2[e + 2];
        float m = sqrtf(gxv * gxv + gyv * gyv + 1e-8f);
        if (!INTERIOR) {
          int gy = Y0 - 1 + r;
          int gx = X0 - 1 + c0 + e;
          m = ((unsigned)gy < IMG_H && (unsigned)gx < IMG_W) ? m : 0.f;
        }
        res[e] = m;
      }
      float4* pd = (float4*)&s_mg[r * MW + c0];
      if (ch == 0) {
        *pd = make_float4(res[0], res[1], res[2], res[3]);
      } else {
        float4 s = *pd;
        s.x += res[0]; s.y += res[1]; s.z += res[2]; s.w += res[3];
        *pd = s;
      }
    }
    __syncthreads();
  }

  // ---- Stage D: band early-out + orientation + NMS (unchanged from R3) ----
  {
    const int ty  = tid >> 3;         // 0..31
    const int tx0 = (tid & 7) << 2;   // 0..28 step 4
    const int row1 = (ty + 1) * MW;

    float4 q0 = *(const float4*)&s_mg[row1 + tx0];
    float4 q1 = *(const float4*)&s_mg[row1 + tx0 + 4];
    float mcs[4];
    mcs[0] = q0.y; mcs[1] = q0.z; mcs[2] = q0.w; mcs[3] = q1.x;

    bool band = false;
#pragma unroll
    for (int e = 0; e < 4; ++e)
      band = band || (mcs[e] >= 6.0f && mcs[e] <= 50.0f);

    float4 resv = make_float4(0.f, 0.f, 0.f, 0.f);
    if (__ballot(band) != 0ULL) {
      float w0[8], w1[8], w2[8];
#pragma unroll
      for (int rr = 0; rr < 3; ++rr) {
        float* w = (rr == 0) ? w0 : (rr == 1) ? w1 : w2;
        float4 p = *(const float4*)&s_bs[(ty + 1 + rr) * BW + tx0];
        float4 q = *(const float4*)&s_bs[(ty + 1 + rr) * BW + tx0 + 4];
        w[0]=p.x; w[1]=p.y; w[2]=p.z; w[3]=p.w; w[4]=q.x; w[5]=q.y; w[6]=q.z; w[7]=q.w;
      }
      const unsigned long long off_tbl = 0xDDDCDBFF23242501ULL;
      float res[4];
#pragma unroll
      for (int e = 0; e < 4; ++e) {
        int tx = tx0 + e;
        float b00 = w0[e + 1], b01 = w0[e + 2], b02 = w0[e + 3];
        float b10 = w1[e + 1],                  b12 = w1[e + 3];
        float b20 = w2[e + 1], b21 = w2[e + 2], b22 = w2[e + 3];
        float gxs = b00 - b02 + 2.f * b10 - 2.f * b12 + b20 - b22;
        float gys = b00 + 2.f * b01 + b02 - b20 - 2.f * b21 - b22;
        float ax = fabsf(gxs), ay = fabsf(gys);
        float f1 = ay - 0.41421356f * ax;
        float f2 = ay - 2.4142137f * ax;
        int off;
        if (fminf(fabsf(f1), fabsf(f2)) < 1e-4f * (ax + ay)) {
          float ori = atan2f(gys, gxs) * 57.295827908797776f + 180.0f;  // 180/3.14159
          int k = (int)rintf(ori / 45.0f);   // round-half-even like jnp.round
          int ip = k & 7;
          off = (int)(signed char)(off_tbl >> (ip * 8));
        } else {
          off = (f1 <= 0.f) ? 1
              : (f2 >= 0.f) ? MW
              : (((__float_as_uint(gxs) ^ __float_as_uint(gys)) >> 31) ? (MW - 1)
                                                                       : (MW + 1));
        }
        int ctr = row1 + (tx + 1);
        float mc  = mcs[e];
        float csp = mc - s_mg[ctr + off];
        float csn = mc - s_mg[ctr - off];
        bool is_max = fminf(csp, csn) > 0.0f;
        bool keep = is_max && (mc >= 6.0f) && (mc <= 50.0f);
        res[e] = keep ? 1.0f : 0.0f;
      }
      resv = make_float4(res[0], res[1], res[2], res[3]);
    }
    *(float4*)&out[(size_t)(Y0 + ty) * IMG_W + (X0 + tx0)] = resv;
  }
}

__global__ __launch_bounds__(256, 6)
void canny_fused(const float* __restrict__ img,
                 const float* __restrict__ gauss,
                 float* __restrict__ out) {
  __shared__ float s_hb[HBH * HBW];  // per-channel horizontal blur (transient)
  __shared__ float s_bl[BH * BW];    // per-channel blurred (transient)
  __shared__ float s_bs[BH * BW];    // sum over channels of blurred
  __shared__ float s_mg[MH * MW];    // grad_mag summed over channels

  const int tid = threadIdx.x;
  const int X0 = blockIdx.x * TW;
  const int Y0 = blockIdx.y * TH;
  const float g0 = gauss[0], g1 = gauss[1], g2 = gauss[2],
              g3 = gauss[3], g4 = gauss[4];

  // Stage A touches rows Y0-4..Y0+35, cols X0-4..X0+39 -> interior iff
  // bx,by in [1,126] (97% of blocks).
  const bool interior = (blockIdx.x >= 1) && (blockIdx.x <= 126) &&
                        (blockIdx.y >= 1) && (blockIdx.y <= 126);
  if (interior)
    pipeline<true >(img, g0, g1, g2, g3, g4, X0, Y0, tid, s_hb, s_bl, s_bs, s_mg, out);
  else
    pipeline<false>(img, g0, g1, g2, g3, g4, X0, Y0, tid, s_hb, s_bl, s_bs, s_mg, out);
}

extern "C" void kernel_launch(void* const* d_in, const int* in_sizes, int n_in,
                              void* d_out, int out_size, void* d_ws, size_t ws_size,
                              hipStream_t stream) {
  const float* img   = (const float*)d_in[0];
  const float* gauss = (const float*)d_in[1];
  float* out = (float*)d_out;
  dim3 grid(IMG_W / TW, IMG_H / TH);
  canny_fused<<<grid, 256, 0, stream>>>(img, gauss, out);
}

// Round 5
// 336.923 us; speedup vs baseline: 1.5373x; 1.0139x over previous
//
#include <hip/hip_runtime.h>

// Fused Canny-style edge pipeline, 1x3x4096x4096 fp32 -> 1x4096x4096 fp32.
// R2: 32x32 tile, group-of-4-column vectorization.
// R3: Stage-D wave-level early-out on the [6,50] magnitude band + guarded
//     comparison-based orientation with bit-exact atan2f fallback. (146 us)
// R4: register pipelining across barriers -> scratch spills. REVERTED.
// R5: interior-block template specialization (142 us). VALUBusy 68 -> now
//     co-limited by LDS conflicts (8.85M cyc) + 9 barrier drains.
// R6: (a) pad s_hb/s_bl rows 40->44 floats (stride 12 mod 32; breaks the
//     r<->r+4 bank alias that made stage A/B/C b128 ops ~4-way conflicted);
//     (b) fuse A(ch+1) into the C(ch) phase: barriers 9->7, A's global loads
//     issued before C so HBM latency hides under C's LDS work. No state held
//     across barriers (R4 lesson). Arithmetic order unchanged.
// R7: identical to R6 — previous round's bench was an infra failure
//     (container acquisition), not a kernel failure; resubmitting unchanged.

#define IMG_H 4096
#define IMG_W 4096

constexpr int TW = 32, TH = 32;
constexpr int HBH = 40, HBW = 44;  // hblur:   (r,c) -> abs (Y0-4+r, X0-2+c)
constexpr int BH  = 36, BW  = 44;  // blurred: (r,c) -> abs (Y0-2+r, X0-2+c)
constexpr int MH  = 34, MW  = 36;  // gradmag: (r,c) -> abs (Y0-1+r, X0-1+c)

// ---------------- Stage D (shared by both pipelines) ----------------
__device__ __forceinline__ void stageD(
    const float* __restrict__ s_bs, const float* __restrict__ s_mg,
    float* __restrict__ out, int X0, int Y0, int tid) {
  const int ty  = tid >> 3;         // 0..31
  const int tx0 = (tid & 7) << 2;   // 0..28 step 4
  const int row1 = (ty + 1) * MW;

  float4 q0 = *(const float4*)&s_mg[row1 + tx0];
  float4 q1 = *(const float4*)&s_mg[row1 + tx0 + 4];
  float mcs[4];
  mcs[0] = q0.y; mcs[1] = q0.z; mcs[2] = q0.w; mcs[3] = q1.x;

  bool band = false;
#pragma unroll
  for (int e = 0; e < 4; ++e)
    band = band || (mcs[e] >= 6.0f && mcs[e] <= 50.0f);

  float4 resv = make_float4(0.f, 0.f, 0.f, 0.f);
  if (__ballot(band) != 0ULL) {
    float w0[8], w1[8], w2[8];
#pragma unroll
    for (int rr = 0; rr < 3; ++rr) {
      float* w = (rr == 0) ? w0 : (rr == 1) ? w1 : w2;
      float4 p = *(const float4*)&s_bs[(ty + 1 + rr) * BW + tx0];
      float4 q = *(const float4*)&s_bs[(ty + 1 + rr) * BW + tx0 + 4];
      w[0]=p.x; w[1]=p.y; w[2]=p.z; w[3]=p.w; w[4]=q.x; w[5]=q.y; w[6]=q.z; w[7]=q.w;
    }
    const unsigned long long off_tbl = 0xDDDCDBFF23242501ULL;
    float res[4];
#pragma unroll
    for (int e = 0; e < 4; ++e) {
      int tx = tx0 + e;
      float b00 = w0[e + 1], b01 = w0[e + 2], b02 = w0[e + 3];
      float b10 = w1[e + 1],                  b12 = w1[e + 3];
      float b20 = w2[e + 1], b21 = w2[e + 2], b22 = w2[e + 3];
      float gxs = b00 - b02 + 2.f * b10 - 2.f * b12 + b20 - b22;
      float gys = b00 + 2.f * b01 + b02 - b20 - 2.f * b21 - b22;
      float ax = fabsf(gxs), ay = fabsf(gys);
      float f1 = ay - 0.41421356f * ax;
      float f2 = ay - 2.4142137f * ax;
      int off;
      if (fminf(fabsf(f1), fabsf(f2)) < 1e-4f * (ax + ay)) {
        float ori = atan2f(gys, gxs) * 57.295827908797776f + 180.0f;  // 180/3.14159
        int k = (int)rintf(ori / 45.0f);   // round-half-even like jnp.round
        int ip = k & 7;
        off = (int)(signed char)(off_tbl >> (ip * 8));
      } else {
        off = (f1 <= 0.f) ? 1
            : (f2 >= 0.f) ? MW
            : (((__float_as_uint(gxs) ^ __float_as_uint(gys)) >> 31) ? (MW - 1)
                                                                     : (MW + 1));
      }
      int ctr = row1 + (tx + 1);
      float mc  = mcs[e];
      float csp = mc - s_mg[ctr + off];
      float csn = mc - s_mg[ctr - off];
      bool is_max = fminf(csp, csn) > 0.0f;
      bool keep = is_max && (mc >= 6.0f) && (mc <= 50.0f);
      res[e] = keep ? 1.0f : 0.0f;
    }
    resv = make_float4(res[0], res[1], res[2], res[3]);
  }
  *(float4*)&out[(size_t)(Y0 + ty) * IMG_W + (X0 + tx0)] = resv;
}

// ---------------- interior pipeline (97% of blocks) ----------------
__device__ __forceinline__ void pipeline_interior(
    const float* __restrict__ img,
    float g0, float g1, float g2, float g3, float g4,
    int X0, int Y0, int tid,
    float* __restrict__ s_hb, float* __restrict__ s_bl,
    float* __restrict__ s_bs, float* __restrict__ s_mg,
    float* __restrict__ out) {

  // channel-invariant task maps
  const int rA0 = tid / 10, cA0 = (tid - rA0 * 10) * 4;   // A: 40x10 = 400
  const int jA1 = tid + 256;
  const int rA1 = jA1 / 10, cA1 = (jA1 - rA1 * 10) * 4;
  const bool hasA1 = (tid < 144);

  float4 pa0, pb0, pa1, pb1;  // A prefetch regs (live only within one phase)

  auto issueA = [&](int ch) {
    const float* im = img + (size_t)ch * ((size_t)IMG_H * IMG_W);
    const float* r0 = im + (size_t)(Y0 - 4 + rA0) * IMG_W + (X0 - 4 + cA0);
    pa0 = *(const float4*)r0;
    pb0 = *(const float4*)(r0 + 4);
    if (hasA1) {
      const float* r1 = im + (size_t)(Y0 - 4 + rA1) * IMG_W + (X0 - 4 + cA1);
      pa1 = *(const float4*)r1;
      pb1 = *(const float4*)(r1 + 4);
    }
  };
  auto storeA = [&]() {
    auto h5 = [&](const float4& a, const float4& b) {
      float4 o;
      o.x = g0 * a.x + g1 * a.y + g2 * a.z + g3 * a.w + g4 * b.x;
      o.y = g0 * a.y + g1 * a.z + g2 * a.w + g3 * b.x + g4 * b.y;
      o.z = g0 * a.z + g1 * a.w + g2 * b.x + g3 * b.y + g4 * b.z;
      o.w = g0 * a.w + g1 * b.x + g2 * b.y + g3 * b.z + g4 * b.w;
      return o;
    };
    *(float4*)&s_hb[rA0 * HBW + cA0] = h5(pa0, pb0);
    if (hasA1) *(float4*)&s_hb[rA1 * HBW + cA1] = h5(pa1, pb1);
  };

  auto stageB = [&](int ch) {
    for (int j = tid; j < BH * 10; j += 256) {
      int r = j / 10, g = j - r * 10;
      int c0 = g * 4;
      const float* p = &s_hb[r * HBW + c0];
      float4 a0 = *(const float4*)(p);
      float4 a1 = *(const float4*)(p + HBW);
      float4 a2 = *(const float4*)(p + 2 * HBW);
      float4 a3 = *(const float4*)(p + 3 * HBW);
      float4 a4 = *(const float4*)(p + 4 * HBW);
      float4 v;
      v.x = g0 * a0.x + g1 * a1.x + g2 * a2.x + g3 * a3.x + g4 * a4.x;
      v.y = g0 * a0.y + g1 * a1.y + g2 * a2.y + g3 * a3.y + g4 * a4.y;
      v.z = g0 * a0.z + g1 * a1.z + g2 * a2.z + g3 * a3.z + g4 * a4.z;
      v.w = g0 * a0.w + g1 * a1.w + g2 * a2.w + g3 * a3.w + g4 * a4.w;
      *(float4*)&s_bl[r * BW + c0] = v;
      float4* ps = (float4*)&s_bs[r * BW + c0];
      if (ch == 0) {
        *ps = v;
      } else {
        float4 s = *ps;
        s.x += v.x; s.y += v.y; s.z += v.z; s.w += v.w;
        *ps = s;
      }
    }
  };

  auto stageC = [&](int ch) {
    for (int j = tid; j < MH * 9; j += 256) {
      int r = j / 9, g = j - r * 9;
      int c0 = g * 4;
      float w0[6], w1[6], w2[6];
      const float* p = &s_bl[r * BW + c0];
      { float4 a = *(const float4*)(p);          float2 b = *(const float2*)(p + 4);
        w0[0]=a.x; w0[1]=a.y; w0[2]=a.z; w0[3]=a.w; w0[4]=b.x; w0[5]=b.y; }
      { float4 a = *(const float4*)(p + BW);     float2 b = *(const float2*)(p + BW + 4);
        w1[0]=a.x; w1[1]=a.y; w1[2]=a.z; w1[3]=a.w; w1[4]=b.x; w1[5]=b.y; }
      { float4 a = *(const float4*)(p + 2 * BW); float2 b = *(const float2*)(p + 2 * BW + 4);
        w2[0]=a.x; w2[1]=a.y; w2[2]=a.z; w2[3]=a.w; w2[4]=b.x; w2[5]=b.y; }
      float res[4];
#pragma unroll
      for (int e = 0; e < 4; ++e) {
        float gxv = w0[e] - w0[e + 2] + 2.f * w1[e] - 2.f * w1[e + 2] + w2[e] - w2[e + 2];
        float gyv = w0[e] + 2.f * w0[e + 1] + w0[e + 2] - w2[e] - 2.f * w2[e + 1] - w2[e + 2];
        res[e] = sqrtf(gxv * gxv + gyv * gyv + 1e-8f);
      }
      float4* pd = (float4*)&s_mg[r * MW + c0];
      if (ch == 0) {
        *pd = make_float4(res[0], res[1], res[2], res[3]);
      } else {
        float4 s = *pd;
        s.x += res[0]; s.y += res[1]; s.z += res[2]; s.w += res[3];
        *pd = s;
      }
    }
  };

  // driver: A(0) | bar | { B | bar | [issueA(ch+1), C, storeA] | bar } x3 | D
  issueA(0);
  storeA();
  __syncthreads();
#pragma unroll
  for (int ch = 0; ch < 3; ++ch) {
    stageB(ch);
    __syncthreads();
    if (ch < 2) issueA(ch + 1);   // loads fly under C's LDS work
    stageC(ch);
    if (ch < 2) storeA();         // s_hb free: B(ch) read it before the barrier
    __syncthreads();
  }
  stageD(s_bs, s_mg, out, X0, Y0, tid);
}

// ---------------- boundary pipeline (3% of blocks, R5 schedule) ----------------
__device__ void pipeline_boundary(
    const float* __restrict__ img,
    float g0, float g1, float g2, float g3, float g4,
    int X0, int Y0, int tid,
    float* __restrict__ s_hb, float* __restrict__ s_bl,
    float* __restrict__ s_bs, float* __restrict__ s_mg,
    float* __restrict__ out) {

  for (int ch = 0; ch < 3; ++ch) {
    const float* im = img + (size_t)ch * ((size_t)IMG_H * IMG_W);

    for (int j = tid; j < HBH * 10; j += 256) {
      int r = j / 10, g = j - r * 10;
      int c0 = g * 4;
      int gy = Y0 - 4 + r;
      float4 o;
      if ((unsigned)gy < IMG_H) {
        int cb = X0 - 4 + c0;
        const float* row = im + (size_t)gy * IMG_W;
        float a0, a1, a2, a3, a4, a5, a6, a7;
        if (cb >= 0 && cb + 7 < IMG_W) {
          float4 va = *(const float4*)(row + cb);
          float4 vb = *(const float4*)(row + cb + 4);
          a0 = va.x; a1 = va.y; a2 = va.z; a3 = va.w;
          a4 = vb.x; a5 = vb.y; a6 = vb.z; a7 = vb.w;
        } else {
          float t[8];
#pragma unroll
          for (int u = 0; u < 8; ++u) {
            int x = cb + u;
            t[u] = ((unsigned)x < IMG_W) ? row[x] : 0.f;
          }
          a0 = t[0]; a1 = t[1]; a2 = t[2]; a3 = t[3];
          a4 = t[4]; a5 = t[5]; a6 = t[6]; a7 = t[7];
        }
        o.x = g0 * a0 + g1 * a1 + g2 * a2 + g3 * a3 + g4 * a4;
        o.y = g0 * a1 + g1 * a2 + g2 * a3 + g3 * a4 + g4 * a5;
        o.z = g0 * a2 + g1 * a3 + g2 * a4 + g3 * a5 + g4 * a6;
        o.w = g0 * a3 + g1 * a4 + g2 * a5 + g3 * a6 + g4 * a7;
      } else {
        o = make_float4(0.f, 0.f, 0.f, 0.f);
      }
      *(float4*)&s_hb[r * HBW + c0] = o;
    }
    __syncthreads();

    for (int j = tid; j < BH * 10; j += 256) {
      int r = j / 10, g = j - r * 10;
      int c0 = g * 4;
      const float* p = &s_hb[r * HBW + c0];
      float4 a0 = *(const float4*)(p);
      float4 a1 = *(const float4*)(p + HBW);
      float4 a2 = *(const float4*)(p + 2 * HBW);
      float4 a3 = *(const float4*)(p + 3 * HBW);
      float4 a4 = *(const float4*)(p + 4 * HBW);
      float4 v;
      v.x = g0 * a0.x + g1 * a1.x + g2 * a2.x + g3 * a3.x + g4 * a4.x;
      v.y = g0 * a0.y + g1 * a1.y + g2 * a2.y + g3 * a3.y + g4 * a4.y;
      v.z = g0 * a0.z + g1 * a1.z + g2 * a2.z + g3 * a3.z + g4 * a4.z;
      v.w = g0 * a0.w + g1 * a1.w + g2 * a2.w + g3 * a3.w + g4 * a4.w;
      {
        int gy = Y0 - 2 + r;
        bool rok = (unsigned)gy < IMG_H;
        int gx0 = X0 - 2 + c0;
        v.x = (rok && (unsigned)(gx0    ) < IMG_W) ? v.x : 0.f;
        v.y = (rok && (unsigned)(gx0 + 1) < IMG_W) ? v.y : 0.f;
        v.z = (rok && (unsigned)(gx0 + 2) < IMG_W) ? v.z : 0.f;
        v.w = (rok && (unsigned)(gx0 + 3) < IMG_W) ? v.w : 0.f;
      }
      *(float4*)&s_bl[r * BW + c0] = v;
      float4* ps = (float4*)&s_bs[r * BW + c0];
      if (ch == 0) {
        *ps = v;
      } else {
        float4 s = *ps;
        s.x += v.x; s.y += v.y; s.z += v.z; s.w += v.w;
        *ps = s;
      }
    }
    __syncthreads();

    for (int j = tid; j < MH * 9; j += 256) {
      int r = j / 9, g = j - r * 9;
      int c0 = g * 4;
      float w0[6], w1[6], w2[6];
      const float* p = &s_bl[r * BW + c0];
      { float4 a = *(const float4*)(p);          float2 b = *(const float2*)(p + 4);
        w0[0]=a.x; w0[1]=a.y; w0[2]=a.z; w0[3]=a.w; w0[4]=b.x; w0[5]=b.y; }
      { float4 a = *(const float4*)(p + BW);     float2 b = *(const float2*)(p + BW + 4);
        w1[0]=a.x; w1[1]=a.y; w1[2]=a.z; w1[3]=a.w; w1[4]=b.x; w1[5]=b.y; }
      { float4 a = *(const float4*)(p + 2 * BW); float2 b = *(const float2*)(p + 2 * BW + 4);
        w2[0]=a.x; w2[1]=a.y; w2[2]=a.z; w2[3]=a.w; w2[4]=b.x; w2[5]=b.y; }
      float res[4];
#pragma unroll
      for (int e = 0; e < 4; ++e) {
        float gxv = w0[e] - w0[e + 2] + 2.f * w1[e] - 2.f * w1[e + 2] + w2[e] - w2[e + 2];
        float gyv = w0[e] + 2.f * w0[e + 1] + w0[e + 2] - w2[e] - 2.f * w2[e + 1] - w2[e + 2];
        float m = sqrtf(gxv * gxv + gyv * gyv + 1e-8f);
        int gy = Y0 - 1 + r;
        int gx = X0 - 1 + c0 + e;
        res[e] = ((unsigned)gy < IMG_H && (unsigned)gx < IMG_W) ? m : 0.f;
      }
      float4* pd = (float4*)&s_mg[r * MW + c0];
      if (ch == 0) {
        *pd = make_float4(res[0], res[1], res[2], res[3]);
      } else {
        float4 s = *pd;
        s.x += res[0]; s.y += res[1]; s.z += res[2]; s.w += res[3];
        *pd = s;
      }
    }
    __syncthreads();
  }
  stageD(s_bs, s_mg, out, X0, Y0, tid);
}

__global__ __launch_bounds__(256, 6)
void canny_fused(const float* __restrict__ img,
                 const float* __restrict__ gauss,
                 float* __restrict__ out) {
  __shared__ float s_hb[HBH * HBW];  // per-channel horizontal blur (transient)
  __shared__ float s_bl[BH * BW];    // per-channel blurred (transient)
  __shared__ float s_bs[BH * BW];    // sum over channels of blurred
  __shared__ float s_mg[MH * MW];    // grad_mag summed over channels

  const int tid = threadIdx.x;
  const int X0 = blockIdx.x * TW;
  const int Y0 = blockIdx.y * TH;
  const float g0 = gauss[0], g1 = gauss[1], g2 = gauss[2],
              g3 = gauss[3], g4 = gauss[4];

  const bool interior = (blockIdx.x >= 1) && (blockIdx.x <= 126) &&
                        (blockIdx.y >= 1) && (blockIdx.y <= 126);
  if (interior)
    pipeline_interior(img, g0, g1, g2, g3, g4, X0, Y0, tid, s_hb, s_bl, s_bs, s_mg, out);
  else
    pipeline_boundary(img, g0, g1, g2, g3, g4, X0, Y0, tid, s_hb, s_bl, s_bs, s_mg, out);
}

extern "C" void kernel_launch(void* const* d_in, const int* in_sizes, int n_in,
                              void* d_out, int out_size, void* d_ws, size_t ws_size,
                              hipStream_t stream) {
  const float* img   = (const float*)d_in[0];
  const float* gauss = (const float*)d_in[1];
  float* out = (float*)d_out;
  dim3 grid(IMG_W / TW, IMG_H / TH);
  canny_fused<<<grid, 256, 0, stream>>>(img, gauss, out);
}

// Round 6
// 332.935 us; speedup vs baseline: 1.5557x; 1.0120x over previous
//
#include <hip/hip_runtime.h>

// Fused Canny-style edge pipeline, 1x3x4096x4096 fp32 -> 1x4096x4096 fp32.
// R3: Stage-D wave-level early-out on the [6,50] band (146 us).
// R4: register pipelining across barriers -> scratch spills. REVERTED.
// R5: interior-block specialization (142 us).
// R6/R7: row pad 40->44 DOUBLED bank conflicts (8.8M->21.5M) -> reverted;
//        A-into-C phase fusion kept (neutral-positive). 140 us, no pipe >65%.
// R8: latency/occupancy attack: (a) s_bs shrunk 36x40 -> 34x36 (only region
//     Stage D reads) => LDS 23040 -> 21952 B => 7 blocks/CU (28 waves, +17%);
//     (b) stride back to 40; (c) Stage-C sqrt-skip: store lb=max(|gx|,|gy|)
//     per channel unless wave has a pixel with lb<=50 (provably identical
//     output: any cheap term alone exceeds 50, preserving band test and
//     NMS comparison signs; exact path taken whenever mg could be <=50).

#define IMG_H 4096
#define IMG_W 4096

constexpr int TW = 32, TH = 32;
constexpr int HBH = 40, HBW = 40;  // hblur:   (r,c) -> abs (Y0-4+r, X0-2+c)
constexpr int BH  = 36, BW  = 40;  // blurred: (r,c) -> abs (Y0-2+r, X0-2+c)
constexpr int SBH = 34, SBW = 36;  // blur-sum: (r,c) -> abs (Y0-1+r, X0-1+c)
constexpr int MH  = 34, MW  = 36;  // gradmag: (r,c) -> abs (Y0-1+r, X0-1+c)

// ---------------- Stage D (shared by both pipelines) ----------------
__device__ __forceinline__ void stageD(
    const float* __restrict__ s_bs, const float* __restrict__ s_mg,
    float* __restrict__ out, int X0, int Y0, int tid) {
  const int ty  = tid >> 3;         // 0..31
  const int tx0 = (tid & 7) << 2;   // 0..28 step 4
  const int row1 = (ty + 1) * MW;

  float4 q0 = *(const float4*)&s_mg[row1 + tx0];
  float4 q1 = *(const float4*)&s_mg[row1 + tx0 + 4];
  float mcs[4];
  mcs[0] = q0.y; mcs[1] = q0.z; mcs[2] = q0.w; mcs[3] = q1.x;

  bool band = false;
#pragma unroll
  for (int e = 0; e < 4; ++e)
    band = band || (mcs[e] >= 6.0f && mcs[e] <= 50.0f);

  float4 resv = make_float4(0.f, 0.f, 0.f, 0.f);
  if (__ballot(band) != 0ULL) {
    float w0[8], w1[8], w2[8];
#pragma unroll
    for (int rr = 0; rr < 3; ++rr) {
      float* w = (rr == 0) ? w0 : (rr == 1) ? w1 : w2;
      // s_bs row (ty+rr) in the 34x36 array == abs row Y0+ty+rr-1+... (same
      // region as the old (ty+1+rr) row of the 36x40 array).
      float4 p = *(const float4*)&s_bs[(ty + rr) * SBW + tx0];
      float4 q = *(const float4*)&s_bs[(ty + rr) * SBW + tx0 + 4];
      w[0]=p.x; w[1]=p.y; w[2]=p.z; w[3]=p.w; w[4]=q.x; w[5]=q.y; w[6]=q.z; w[7]=q.w;
    }
    const unsigned long long off_tbl = 0xDDDCDBFF23242501ULL;
    float res[4];
#pragma unroll
    for (int e = 0; e < 4; ++e) {
      int tx = tx0 + e;
      float b00 = w0[e + 1], b01 = w0[e + 2], b02 = w0[e + 3];
      float b10 = w1[e + 1],                  b12 = w1[e + 3];
      float b20 = w2[e + 1], b21 = w2[e + 2], b22 = w2[e + 3];
      float gxs = b00 - b02 + 2.f * b10 - 2.f * b12 + b20 - b22;
      float gys = b00 + 2.f * b01 + b02 - b20 - 2.f * b21 - b22;
      float ax = fabsf(gxs), ay = fabsf(gys);
      float f1 = ay - 0.41421356f * ax;
      float f2 = ay - 2.4142137f * ax;
      int off;
      if (fminf(fabsf(f1), fabsf(f2)) < 1e-4f * (ax + ay)) {
        float ori = atan2f(gys, gxs) * 57.295827908797776f + 180.0f;  // 180/3.14159
        int k = (int)rintf(ori / 45.0f);   // round-half-even like jnp.round
        int ip = k & 7;
        off = (int)(signed char)(off_tbl >> (ip * 8));
      } else {
        off = (f1 <= 0.f) ? 1
            : (f2 >= 0.f) ? MW
            : (((__float_as_uint(gxs) ^ __float_as_uint(gys)) >> 31) ? (MW - 1)
                                                                     : (MW + 1));
      }
      int ctr = row1 + (tx + 1);
      float mc  = mcs[e];
      float csp = mc - s_mg[ctr + off];
      float csn = mc - s_mg[ctr - off];
      bool is_max = fminf(csp, csn) > 0.0f;
      bool keep = is_max && (mc >= 6.0f) && (mc <= 50.0f);
      res[e] = keep ? 1.0f : 0.0f;
    }
    resv = make_float4(res[0], res[1], res[2], res[3]);
  }
  *(float4*)&out[(size_t)(Y0 + ty) * IMG_W + (X0 + tx0)] = resv;
}

// ---------------- interior pipeline (97% of blocks) ----------------
__device__ __forceinline__ void pipeline_interior(
    const float* __restrict__ img,
    float g0, float g1, float g2, float g3, float g4,
    int X0, int Y0, int tid,
    float* __restrict__ s_hb, float* __restrict__ s_bl,
    float* __restrict__ s_bs, float* __restrict__ s_mg,
    float* __restrict__ out) {

  // channel-invariant task maps
  const int rA0 = tid / 10, cA0 = (tid - rA0 * 10) * 4;   // A: 40x10 = 400
  const int jA1 = tid + 256;
  const int rA1 = jA1 / 10, cA1 = (jA1 - rA1 * 10) * 4;
  const bool hasA1 = (tid < 144);

  float4 pa0, pb0, pa1, pb1;  // A prefetch regs (live only within one phase)

  auto issueA = [&](int ch) {
    const float* im = img + (size_t)ch * ((size_t)IMG_H * IMG_W);
    const float* r0 = im + (size_t)(Y0 - 4 + rA0) * IMG_W + (X0 - 4 + cA0);
    pa0 = *(const float4*)r0;
    pb0 = *(const float4*)(r0 + 4);
    if (hasA1) {
      const float* r1 = im + (size_t)(Y0 - 4 + rA1) * IMG_W + (X0 - 4 + cA1);
      pa1 = *(const float4*)r1;
      pb1 = *(const float4*)(r1 + 4);
    }
  };
  auto storeA = [&]() {
    auto h5 = [&](const float4& a, const float4& b) {
      float4 o;
      o.x = g0 * a.x + g1 * a.y + g2 * a.z + g3 * a.w + g4 * b.x;
      o.y = g0 * a.y + g1 * a.z + g2 * a.w + g3 * b.x + g4 * b.y;
      o.z = g0 * a.z + g1 * a.w + g2 * b.x + g3 * b.y + g4 * b.z;
      o.w = g0 * a.w + g1 * b.x + g2 * b.y + g3 * b.z + g4 * b.w;
      return o;
    };
    *(float4*)&s_hb[rA0 * HBW + cA0] = h5(pa0, pb0);
    if (hasA1) *(float4*)&s_hb[rA1 * HBW + cA1] = h5(pa1, pb1);
  };

  auto stageB = [&](int ch) {
    for (int j = tid; j < BH * 10; j += 256) {
      int r = j / 10, g = j - r * 10;
      int c0 = g * 4;
      const float* p = &s_hb[r * HBW + c0];
      float4 a0 = *(const float4*)(p);
      float4 a1 = *(const float4*)(p + HBW);
      float4 a2 = *(const float4*)(p + 2 * HBW);
      float4 a3 = *(const float4*)(p + 3 * HBW);
      float4 a4 = *(const float4*)(p + 4 * HBW);
      float4 v;
      v.x = g0 * a0.x + g1 * a1.x + g2 * a2.x + g3 * a3.x + g4 * a4.x;
      v.y = g0 * a0.y + g1 * a1.y + g2 * a2.y + g3 * a3.y + g4 * a4.y;
      v.z = g0 * a0.z + g1 * a1.z + g2 * a2.z + g3 * a3.z + g4 * a4.z;
      v.w = g0 * a0.w + g1 * a1.w + g2 * a2.w + g3 * a3.w + g4 * a4.w;
      *(float4*)&s_bl[r * BW + c0] = v;
      // s_bs only covers rows 1..34, cols 0..35 (all Stage D ever reads).
      if ((unsigned)(r - 1) < (unsigned)SBH && c0 < SBW) {
        float4* ps = (float4*)&s_bs[(r - 1) * SBW + c0];
        if (ch == 0) {
          *ps = v;
        } else {
          float4 s = *ps;
          s.x += v.x; s.y += v.y; s.z += v.z; s.w += v.w;
          *ps = s;
        }
      }
    }
  };

  auto stageC = [&](int ch) {
    for (int j = tid; j < MH * 9; j += 256) {
      int r = j / 9, g = j - r * 9;
      int c0 = g * 4;
      float w0[6], w1[6], w2[6];
      const float* p = &s_bl[r * BW + c0];
      { float4 a = *(const float4*)(p);          float2 b = *(const float2*)(p + 4);
        w0[0]=a.x; w0[1]=a.y; w0[2]=a.z; w0[3]=a.w; w0[4]=b.x; w0[5]=b.y; }
      { float4 a = *(const float4*)(p + BW);     float2 b = *(const float2*)(p + BW + 4);
        w1[0]=a.x; w1[1]=a.y; w1[2]=a.z; w1[3]=a.w; w1[4]=b.x; w1[5]=b.y; }
      { float4 a = *(const float4*)(p + 2 * BW); float2 b = *(const float2*)(p + 2 * BW + 4);
        w2[0]=a.x; w2[1]=a.y; w2[2]=a.z; w2[3]=a.w; w2[4]=b.x; w2[5]=b.y; }
      float gxv[4], gyv[4], lb[4];
#pragma unroll
      for (int e = 0; e < 4; ++e) {
        gxv[e] = w0[e] - w0[e + 2] + 2.f * w1[e] - 2.f * w1[e + 2] + w2[e] - w2[e + 2];
        gyv[e] = w0[e] + 2.f * w0[e + 1] + w0[e + 2] - w2[e] - 2.f * w2[e + 1] - w2[e + 2];
        lb[e] = fmaxf(fabsf(gxv[e]), fabsf(gyv[e]));  // lb <= sqrt(gx^2+gy^2+eps)
      }
      float lbmin = fminf(fminf(lb[0], lb[1]), fminf(lb[2], lb[3]));
      float res[4];
      // Exact magnitude needed only if some pixel in the wave could end with
      // channel-sum mg <= 50 (requires every channel's lb <= 50). Cheap terms
      // alone exceed 50, so stored sums preserve the band test and all NMS
      // comparison signs exactly.
      if (__ballot(lbmin <= 50.0f) != 0ULL) {
#pragma unroll
        for (int e = 0; e < 4; ++e)
          res[e] = sqrtf(gxv[e] * gxv[e] + gyv[e] * gyv[e] + 1e-8f);
      } else {
#pragma unroll
        for (int e = 0; e < 4; ++e)
          res[e] = lb[e];
      }
      float4* pd = (float4*)&s_mg[r * MW + c0];
      if (ch == 0) {
        *pd = make_float4(res[0], res[1], res[2], res[3]);
      } else {
        float4 s = *pd;
        s.x += res[0]; s.y += res[1]; s.z += res[2]; s.w += res[3];
        *pd = s;
      }
    }
  };

  // driver: A(0) | bar | { B | bar | [issueA(ch+1), C, storeA] | bar } x3 | D
  issueA(0);
  storeA();
  __syncthreads();
#pragma unroll
  for (int ch = 0; ch < 3; ++ch) {
    stageB(ch);
    __syncthreads();
    if (ch < 2) issueA(ch + 1);   // loads fly under C's LDS work
    stageC(ch);
    if (ch < 2) storeA();         // s_hb free: B(ch) read it before the barrier
    __syncthreads();
  }
  stageD(s_bs, s_mg, out, X0, Y0, tid);
}

// ---------------- boundary pipeline (3% of blocks) ----------------
__device__ void pipeline_boundary(
    const float* __restrict__ img,
    float g0, float g1, float g2, float g3, float g4,
    int X0, int Y0, int tid,
    float* __restrict__ s_hb, float* __restrict__ s_bl,
    float* __restrict__ s_bs, float* __restrict__ s_mg,
    float* __restrict__ out) {

  for (int ch = 0; ch < 3; ++ch) {
    const float* im = img + (size_t)ch * ((size_t)IMG_H * IMG_W);

    for (int j = tid; j < HBH * 10; j += 256) {
      int r = j / 10, g = j - r * 10;
      int c0 = g * 4;
      int gy = Y0 - 4 + r;
      float4 o;
      if ((unsigned)gy < IMG_H) {
        int cb = X0 - 4 + c0;
        const float* row = im + (size_t)gy * IMG_W;
        float a0, a1, a2, a3, a4, a5, a6, a7;
        if (cb >= 0 && cb + 7 < IMG_W) {
          float4 va = *(const float4*)(row + cb);
          float4 vb = *(const float4*)(row + cb + 4);
          a0 = va.x; a1 = va.y; a2 = va.z; a3 = va.w;
          a4 = vb.x; a5 = vb.y; a6 = vb.z; a7 = vb.w;
        } else {
          float t[8];
#pragma unroll
          for (int u = 0; u < 8; ++u) {
            int x = cb + u;
            t[u] = ((unsigned)x < IMG_W) ? row[x] : 0.f;
          }
          a0 = t[0]; a1 = t[1]; a2 = t[2]; a3 = t[3];
          a4 = t[4]; a5 = t[5]; a6 = t[6]; a7 = t[7];
        }
        o.x = g0 * a0 + g1 * a1 + g2 * a2 + g3 * a3 + g4 * a4;
        o.y = g0 * a1 + g1 * a2 + g2 * a3 + g3 * a4 + g4 * a5;
        o.z = g0 * a2 + g1 * a3 + g2 * a4 + g3 * a5 + g4 * a6;
        o.w = g0 * a3 + g1 * a4 + g2 * a5 + g3 * a6 + g4 * a7;
      } else {
        o = make_float4(0.f, 0.f, 0.f, 0.f);
      }
      *(float4*)&s_hb[r * HBW + c0] = o;
    }
    __syncthreads();

    for (int j = tid; j < BH * 10; j += 256) {
      int r = j / 10, g = j - r * 10;
      int c0 = g * 4;
      const float* p = &s_hb[r * HBW + c0];
      float4 a0 = *(const float4*)(p);
      float4 a1 = *(const float4*)(p + HBW);
      float4 a2 = *(const float4*)(p + 2 * HBW);
      float4 a3 = *(const float4*)(p + 3 * HBW);
      float4 a4 = *(const float4*)(p + 4 * HBW);
      float4 v;
      v.x = g0 * a0.x + g1 * a1.x + g2 * a2.x + g3 * a3.x + g4 * a4.x;
      v.y = g0 * a0.y + g1 * a1.y + g2 * a2.y + g3 * a3.y + g4 * a4.y;
      v.z = g0 * a0.z + g1 * a1.z + g2 * a2.z + g3 * a3.z + g4 * a4.z;
      v.w = g0 * a0.w + g1 * a1.w + g2 * a2.w + g3 * a3.w + g4 * a4.w;
      {
        int gy = Y0 - 2 + r;
        bool rok = (unsigned)gy < IMG_H;
        int gx0 = X0 - 2 + c0;
        v.x = (rok && (unsigned)(gx0    ) < IMG_W) ? v.x : 0.f;
        v.y = (rok && (unsigned)(gx0 + 1) < IMG_W) ? v.y : 0.f;
        v.z = (rok && (unsigned)(gx0 + 2) < IMG_W) ? v.z : 0.f;
        v.w = (rok && (unsigned)(gx0 + 3) < IMG_W) ? v.w : 0.f;
      }
      *(float4*)&s_bl[r * BW + c0] = v;
      if ((unsigned)(r - 1) < (unsigned)SBH && c0 < SBW) {
        float4* ps = (float4*)&s_bs[(r - 1) * SBW + c0];
        if (ch == 0) {
          *ps = v;
        } else {
          float4 s = *ps;
          s.x += v.x; s.y += v.y; s.z += v.z; s.w += v.w;
          *ps = s;
        }
      }
    }
    __syncthreads();

    for (int j = tid; j < MH * 9; j += 256) {
      int r = j / 9, g = j - r * 9;
      int c0 = g * 4;
      float w0[6], w1[6], w2[6];
      const float* p = &s_bl[r * BW + c0];
      { float4 a = *(const float4*)(p);          float2 b = *(const float2*)(p + 4);
        w0[0]=a.x; w0[1]=a.y; w0[2]=a.z; w0[3]=a.w; w0[4]=b.x; w0[5]=b.y; }
      { float4 a = *(const float4*)(p + BW);     float2 b = *(const float2*)(p + BW + 4);
        w1[0]=a.x; w1[1]=a.y; w1[2]=a.z; w1[3]=a.w; w1[4]=b.x; w1[5]=b.y; }
      { float4 a = *(const float4*)(p + 2 * BW); float2 b = *(const float2*)(p + 2 * BW + 4);
        w2[0]=a.x; w2[1]=a.y; w2[2]=a.z; w2[3]=a.w; w2[4]=b.x; w2[5]=b.y; }
      float res[4];
#pragma unroll
      for (int e = 0; e < 4; ++e) {
        float gxv = w0[e] - w0[e + 2] + 2.f * w1[e] - 2.f * w1[e + 2] + w2[e] - w2[e + 2];
        float gyv = w0[e] + 2.f * w0[e + 1] + w0[e + 2] - w2[e] - 2.f * w2[e + 1] - w2[e + 2];
        float m = sqrtf(gxv * gxv + gyv * gyv + 1e-8f);
        int gy = Y0 - 1 + r;
        int gx = X0 - 1 + c0 + e;
        res[e] = ((unsigned)gy < IMG_H && (unsigned)gx < IMG_W) ? m : 0.f;
      }
      float4* pd = (float4*)&s_mg[r * MW + c0];
      if (ch == 0) {
        *pd = make_float4(res[0], res[1], res[2], res[3]);
      } else {
        float4 s = *pd;
        s.x += res[0]; s.y += res[1]; s.z += res[2]; s.w += res[3];
        *pd = s;
      }
    }
    __syncthreads();
  }
  stageD(s_bs, s_mg, out, X0, Y0, tid);
}

__global__ __launch_bounds__(256, 7)
void canny_fused(const float* __restrict__ img,
                 const float* __restrict__ gauss,
                 float* __restrict__ out) {
  __shared__ float s_hb[HBH * HBW];   // 6400 B
  __shared__ float s_bl[BH * BW];     // 5760 B
  __shared__ float s_bs[SBH * SBW];   // 4896 B (shrunk to Stage-D region)
  __shared__ float s_mg[MH * MW];     // 4896 B -> total 21952 B, 7 blocks/CU

  const int tid = threadIdx.x;
  const int X0 = blockIdx.x * TW;
  const int Y0 = blockIdx.y * TH;
  const float g0 = gauss[0], g1 = gauss[1], g2 = gauss[2],
              g3 = gauss[3], g4 = gauss[4];

  const bool interior = (blockIdx.x >= 1) && (blockIdx.x <= 126) &&
                        (blockIdx.y >= 1) && (blockIdx.y <= 126);
  if (interior)
    pipeline_interior(img, g0, g1, g2, g3, g4, X0, Y0, tid, s_hb, s_bl, s_bs, s_mg, out);
  else
    pipeline_boundary(img, g0, g1, g2, g3, g4, X0, Y0, tid, s_hb, s_bl, s_bs, s_mg, out);
}

extern "C" void kernel_launch(void* const* d_in, const int* in_sizes, int n_in,
                              void* d_out, int out_size, void* d_ws, size_t ws_size,
                              hipStream_t stream) {
  const float* img   = (const float*)d_in[0];
  const float* gauss = (const float*)d_in[1];
  float* out = (float*)d_out;
  dim3 grid(IMG_W / TW, IMG_H / TH);
  canny_fused<<<grid, 256, 0, stream>>>(img, gauss, out);
}

// Round 7
// 313.807 us; speedup vs baseline: 1.6505x; 1.0610x over previous
//
#include <hip/hip_runtime.h>

// Fused Canny-style edge pipeline, 1x3x4096x4096 fp32 -> 1x4096x4096 fp32.
// R3: Stage-D wave early-out on the [6,50] band (146 us).
// R4: register pipelining across barriers -> scratch spills. REVERTED.
// R5: interior-block specialization (142 us).
// R6/R7: pad 40->44 doubled bank conflicts. REVERTED. A-into-C fusion kept.
// R8: s_bs shrunk to 34x36 -> 22.0 KB LDS, 7 blocks/CU; sqrt-skip. (131 us)
// R9: packed-fp32 rewrite: stages A/B/C computed on ext_vector_type(4)
//     floats so LLVM emits v_pk_fma_f32/v_pk_add_f32 (full-rate dual fp32
//     on CDNA) — halves the FMA-core instruction count. Same elementwise
//     expression trees -> bit-identical. B/C task maps hoisted out of the
//     channel loop (channel-invariant ints, R8-safe).

#define IMG_H 4096
#define IMG_W 4096

typedef float v4f __attribute__((ext_vector_type(4)));
typedef float v2f __attribute__((ext_vector_type(2)));

constexpr int TW = 32, TH = 32;
constexpr int HBH = 40, HBW = 40;  // hblur:   (r,c) -> abs (Y0-4+r, X0-2+c)
constexpr int BH  = 36, BW  = 40;  // blurred: (r,c) -> abs (Y0-2+r, X0-2+c)
constexpr int SBH = 34, SBW = 36;  // blur-sum: (r,c) -> abs (Y0-1+r, X0-1+c)
constexpr int MH  = 34, MW  = 36;  // gradmag: (r,c) -> abs (Y0-1+r, X0-1+c)

// ---------------- Stage D (shared by both pipelines) ----------------
__device__ __forceinline__ void stageD(
    const float* __restrict__ s_bs, const float* __restrict__ s_mg,
    float* __restrict__ out, int X0, int Y0, int tid) {
  const int ty  = tid >> 3;         // 0..31
  const int tx0 = (tid & 7) << 2;   // 0..28 step 4
  const int row1 = (ty + 1) * MW;

  float4 q0 = *(const float4*)&s_mg[row1 + tx0];
  float4 q1 = *(const float4*)&s_mg[row1 + tx0 + 4];
  float mcs[4];
  mcs[0] = q0.y; mcs[1] = q0.z; mcs[2] = q0.w; mcs[3] = q1.x;

  bool band = false;
#pragma unroll
  for (int e = 0; e < 4; ++e)
    band = band || (mcs[e] >= 6.0f && mcs[e] <= 50.0f);

  float4 resv = make_float4(0.f, 0.f, 0.f, 0.f);
  if (__ballot(band) != 0ULL) {
    float w0[8], w1[8], w2[8];
#pragma unroll
    for (int rr = 0; rr < 3; ++rr) {
      float* w = (rr == 0) ? w0 : (rr == 1) ? w1 : w2;
      float4 p = *(const float4*)&s_bs[(ty + rr) * SBW + tx0];
      float4 q = *(const float4*)&s_bs[(ty + rr) * SBW + tx0 + 4];
      w[0]=p.x; w[1]=p.y; w[2]=p.z; w[3]=p.w; w[4]=q.x; w[5]=q.y; w[6]=q.z; w[7]=q.w;
    }
    const unsigned long long off_tbl = 0xDDDCDBFF23242501ULL;
    float res[4];
#pragma unroll
    for (int e = 0; e < 4; ++e) {
      int tx = tx0 + e;
      float b00 = w0[e + 1], b01 = w0[e + 2], b02 = w0[e + 3];
      float b10 = w1[e + 1],                  b12 = w1[e + 3];
      float b20 = w2[e + 1], b21 = w2[e + 2], b22 = w2[e + 3];
      float gxs = b00 - b02 + 2.f * b10 - 2.f * b12 + b20 - b22;
      float gys = b00 + 2.f * b01 + b02 - b20 - 2.f * b21 - b22;
      float ax = fabsf(gxs), ay = fabsf(gys);
      float f1 = ay - 0.41421356f * ax;
      float f2 = ay - 2.4142137f * ax;
      int off;
      if (fminf(fabsf(f1), fabsf(f2)) < 1e-4f * (ax + ay)) {
        float ori = atan2f(gys, gxs) * 57.295827908797776f + 180.0f;  // 180/3.14159
        int k = (int)rintf(ori / 45.0f);   // round-half-even like jnp.round
        int ip = k & 7;
        off = (int)(signed char)(off_tbl >> (ip * 8));
      } else {
        off = (f1 <= 0.f) ? 1
            : (f2 >= 0.f) ? MW
            : (((__float_as_uint(gxs) ^ __float_as_uint(gys)) >> 31) ? (MW - 1)
                                                                     : (MW + 1));
      }
      int ctr = row1 + (tx + 1);
      float mc  = mcs[e];
      float csp = mc - s_mg[ctr + off];
      float csn = mc - s_mg[ctr - off];
      bool is_max = fminf(csp, csn) > 0.0f;
      bool keep = is_max && (mc >= 6.0f) && (mc <= 50.0f);
      res[e] = keep ? 1.0f : 0.0f;
    }
    resv = make_float4(res[0], res[1], res[2], res[3]);
  }
  *(float4*)&out[(size_t)(Y0 + ty) * IMG_W + (X0 + tx0)] = resv;
}

// ---------------- interior pipeline (97% of blocks) ----------------
__device__ __forceinline__ void pipeline_interior(
    const float* __restrict__ img,
    float g0, float g1, float g2, float g3, float g4,
    int X0, int Y0, int tid,
    float* __restrict__ s_hb, float* __restrict__ s_bl,
    float* __restrict__ s_bs, float* __restrict__ s_mg,
    float* __restrict__ out) {

  // channel-invariant task maps, hoisted (small ints: safe across barriers)
  const int rA0 = tid / 10, cA0 = (tid - rA0 * 10) * 4;   // A: 40x10 = 400
  const int jA1 = tid + 256;
  const int rA1 = jA1 / 10, cA1 = (jA1 - rA1 * 10) * 4;
  const bool hasA1 = (tid < 144);
  const bool hasB1 = (tid < 104);                          // B: 36x10 = 360
  const int rC0 = tid / 9,  cC0 = (tid - rC0 * 9) * 4;     // C: 34x9 = 306
  const int jC1 = tid + 256;
  const int rC1 = jC1 / 9,  cC1 = (jC1 - rC1 * 9) * 4;
  const bool hasC1 = (tid < 50);

  v4f pa0, pb0, pa1, pb1;  // A prefetch regs (live only within one phase)

  auto issueA = [&](int ch) {
    const float* im = img + (size_t)ch * ((size_t)IMG_H * IMG_W);
    const float* r0 = im + (size_t)(Y0 - 4 + rA0) * IMG_W + (X0 - 4 + cA0);
    pa0 = *(const v4f*)r0;
    pb0 = *(const v4f*)(r0 + 4);
    if (hasA1) {
      const float* r1 = im + (size_t)(Y0 - 4 + rA1) * IMG_W + (X0 - 4 + cA1);
      pa1 = *(const v4f*)r1;
      pb1 = *(const v4f*)(r1 + 4);
    }
  };
  auto storeA = [&]() {
    auto h5 = [&](v4f a, v4f b) {
      v4f A1 = __builtin_shufflevector(a, b, 1, 2, 3, 4);
      v4f A2 = __builtin_shufflevector(a, b, 2, 3, 4, 5);
      v4f A3 = __builtin_shufflevector(a, b, 3, 4, 5, 6);
      return g0 * a + g1 * A1 + g2 * A2 + g3 * A3 + g4 * b;
    };
    *(v4f*)&s_hb[rA0 * HBW + cA0] = h5(pa0, pb0);
    if (hasA1) *(v4f*)&s_hb[rA1 * HBW + cA1] = h5(pa1, pb1);
  };

  auto doB = [&](int ch, int r, int c0) {
    const float* p = &s_hb[r * HBW + c0];
    v4f a0 = *(const v4f*)(p);
    v4f a1 = *(const v4f*)(p + HBW);
    v4f a2 = *(const v4f*)(p + 2 * HBW);
    v4f a3 = *(const v4f*)(p + 3 * HBW);
    v4f a4 = *(const v4f*)(p + 4 * HBW);
    v4f v = g0 * a0 + g1 * a1 + g2 * a2 + g3 * a3 + g4 * a4;
    *(v4f*)&s_bl[r * BW + c0] = v;
    // s_bs only covers rows 1..34, cols 0..35 (all Stage D ever reads).
    if ((unsigned)(r - 1) < (unsigned)SBH && c0 < SBW) {
      v4f* ps = (v4f*)&s_bs[(r - 1) * SBW + c0];
      if (ch == 0) *ps = v; else *ps = *ps + v;
    }
  };

  auto doC = [&](int ch, int r, int c0) {
    const float* p = &s_bl[r * BW + c0];
    v4f p0 = *(const v4f*)(p);
    v2f e0 = *(const v2f*)(p + 4);
    v4f p1 = *(const v4f*)(p + BW);
    v2f e1 = *(const v2f*)(p + BW + 4);
    v4f p2 = *(const v4f*)(p + 2 * BW);
    v2f e2 = *(const v2f*)(p + 2 * BW + 4);
    v4f q0 = {e0.x, e0.y, 0.f, 0.f};
    v4f q1 = {e1.x, e1.y, 0.f, 0.f};
    v4f q2 = {e2.x, e2.y, 0.f, 0.f};
    v4f r0_1 = __builtin_shufflevector(p0, q0, 1, 2, 3, 4);
    v4f r0_2 = __builtin_shufflevector(p0, q0, 2, 3, 4, 5);
    v4f r1_0 = p1;
    v4f r1_2 = __builtin_shufflevector(p1, q1, 2, 3, 4, 5);
    v4f r2_1 = __builtin_shufflevector(p2, q2, 1, 2, 3, 4);
    v4f r2_2 = __builtin_shufflevector(p2, q2, 2, 3, 4, 5);
    // same elementwise expression trees as the scalar version
    v4f gx = p0 - r0_2 + 2.f * r1_0 - 2.f * r1_2 + p2 - r2_2;
    v4f gy = p0 + 2.f * r0_1 + r0_2 - p2 - 2.f * r2_1 - r2_2;
    float lb0 = fmaxf(fabsf(gx.x), fabsf(gy.x));
    float lb1 = fmaxf(fabsf(gx.y), fabsf(gy.y));
    float lb2 = fmaxf(fabsf(gx.z), fabsf(gy.z));
    float lb3 = fmaxf(fabsf(gx.w), fabsf(gy.w));
    float lbmin = fminf(fminf(lb0, lb1), fminf(lb2, lb3));
    v4f res;
    // Exact magnitude only if some lane's pixel could end with mg <= 50;
    // otherwise a per-channel lower bound > 50 preserves band test and all
    // NMS comparison signs exactly (see R8 note).
    if (__ballot(lbmin <= 50.0f) != 0ULL) {
      v4f m2 = gx * gx + gy * gy + 1e-8f;
      res.x = sqrtf(m2.x); res.y = sqrtf(m2.y);
      res.z = sqrtf(m2.z); res.w = sqrtf(m2.w);
    } else {
      res = (v4f){lb0, lb1, lb2, lb3};
    }
    v4f* pd = (v4f*)&s_mg[r * MW + c0];
    if (ch == 0) *pd = res; else *pd = *pd + res;
  };

  // driver: A(0) | bar | { B | bar | [issueA(ch+1), C, storeA] | bar } x3 | D
  issueA(0);
  storeA();
  __syncthreads();
#pragma unroll
  for (int ch = 0; ch < 3; ++ch) {
    doB(ch, rA0, cA0);
    if (hasB1) doB(ch, rA1, cA1);
    __syncthreads();
    if (ch < 2) issueA(ch + 1);   // loads fly under C's LDS work
    doC(ch, rC0, cC0);
    if (hasC1) doC(ch, rC1, cC1);
    if (ch < 2) storeA();         // s_hb free: B(ch) read it before the barrier
    __syncthreads();
  }
  stageD(s_bs, s_mg, out, X0, Y0, tid);
}

// ---------------- boundary pipeline (3% of blocks, scalar R8 path) ----------------
__device__ void pipeline_boundary(
    const float* __restrict__ img,
    float g0, float g1, float g2, float g3, float g4,
    int X0, int Y0, int tid,
    float* __restrict__ s_hb, float* __restrict__ s_bl,
    float* __restrict__ s_bs, float* __restrict__ s_mg,
    float* __restrict__ out) {

  for (int ch = 0; ch < 3; ++ch) {
    const float* im = img + (size_t)ch * ((size_t)IMG_H * IMG_W);

    for (int j = tid; j < HBH * 10; j += 256) {
      int r = j / 10, g = j - r * 10;
      int c0 = g * 4;
      int gy = Y0 - 4 + r;
      float4 o;
      if ((unsigned)gy < IMG_H) {
        int cb = X0 - 4 + c0;
        const float* row = im + (size_t)gy * IMG_W;
        float a0, a1, a2, a3, a4, a5, a6, a7;
        if (cb >= 0 && cb + 7 < IMG_W) {
          float4 va = *(const float4*)(row + cb);
          float4 vb = *(const float4*)(row + cb + 4);
          a0 = va.x; a1 = va.y; a2 = va.z; a3 = va.w;
          a4 = vb.x; a5 = vb.y; a6 = vb.z; a7 = vb.w;
        } else {
          float t[8];
#pragma unroll
          for (int u = 0; u < 8; ++u) {
            int x = cb + u;
            t[u] = ((unsigned)x < IMG_W) ? row[x] : 0.f;
          }
          a0 = t[0]; a1 = t[1]; a2 = t[2]; a3 = t[3];
          a4 = t[4]; a5 = t[5]; a6 = t[6]; a7 = t[7];
        }
        o.x = g0 * a0 + g1 * a1 + g2 * a2 + g3 * a3 + g4 * a4;
        o.y = g0 * a1 + g1 * a2 + g2 * a3 + g3 * a4 + g4 * a5;
        o.z = g0 * a2 + g1 * a3 + g2 * a4 + g3 * a5 + g4 * a6;
        o.w = g0 * a3 + g1 * a4 + g2 * a5 + g3 * a6 + g4 * a7;
      } else {
        o = make_float4(0.f, 0.f, 0.f, 0.f);
      }
      *(float4*)&s_hb[r * HBW + c0] = o;
    }
    __syncthreads();

    for (int j = tid; j < BH * 10; j += 256) {
      int r = j / 10, g = j - r * 10;
      int c0 = g * 4;
      const float* p = &s_hb[r * HBW + c0];
      float4 a0 = *(const float4*)(p);
      float4 a1 = *(const float4*)(p + HBW);
      float4 a2 = *(const float4*)(p + 2 * HBW);
      float4 a3 = *(const float4*)(p + 3 * HBW);
      float4 a4 = *(const float4*)(p + 4 * HBW);
      float4 v;
      v.x = g0 * a0.x + g1 * a1.x + g2 * a2.x + g3 * a3.x + g4 * a4.x;
      v.y = g0 * a0.y + g1 * a1.y + g2 * a2.y + g3 * a3.y + g4 * a4.y;
      v.z = g0 * a0.z + g1 * a1.z + g2 * a2.z + g3 * a3.z + g4 * a4.z;
      v.w = g0 * a0.w + g1 * a1.w + g2 * a2.w + g3 * a3.w + g4 * a4.w;
      {
        int gy = Y0 - 2 + r;
        bool rok = (unsigned)gy < IMG_H;
        int gx0 = X0 - 2 + c0;
        v.x = (rok && (unsigned)(gx0    ) < IMG_W) ? v.x : 0.f;
        v.y = (rok && (unsigned)(gx0 + 1) < IMG_W) ? v.y : 0.f;
        v.z = (rok && (unsigned)(gx0 + 2) < IMG_W) ? v.z : 0.f;
        v.w = (rok && (unsigned)(gx0 + 3) < IMG_W) ? v.w : 0.f;
      }
      *(float4*)&s_bl[r * BW + c0] = v;
      if ((unsigned)(r - 1) < (unsigned)SBH && c0 < SBW) {
        float4* ps = (float4*)&s_bs[(r - 1) * SBW + c0];
        if (ch == 0) {
          *ps = v;
        } else {
          float4 s = *ps;
          s.x += v.x; s.y += v.y; s.z += v.z; s.w += v.w;
          *ps = s;
        }
      }
    }
    __syncthreads();

    for (int j = tid; j < MH * 9; j += 256) {
      int r = j / 9, g = j - r * 9;
      int c0 = g * 4;
      float w0[6], w1[6], w2[6];
      const float* p = &s_bl[r * BW + c0];
      { float4 a = *(const float4*)(p);          float2 b = *(const float2*)(p + 4);
        w0[0]=a.x; w0[1]=a.y; w0[2]=a.z; w0[3]=a.w; w0[4]=b.x; w0[5]=b.y; }
      { float4 a = *(const float4*)(p + BW);     float2 b = *(const float2*)(p + BW + 4);
        w1[0]=a.x; w1[1]=a.y; w1[2]=a.z; w1[3]=a.w; w1[4]=b.x; w1[5]=b.y; }
      { float4 a = *(const float4*)(p + 2 * BW); float2 b = *(const float2*)(p + 2 * BW + 4);
        w2[0]=a.x; w2[1]=a.y; w2[2]=a.z; w2[3]=a.w; w2[4]=b.x; w2[5]=b.y; }
      float res[4];
#pragma unroll
      for (int e = 0; e < 4; ++e) {
        float gxv = w0[e] - w0[e + 2] + 2.f * w1[e] - 2.f * w1[e + 2] + w2[e] - w2[e + 2];
        float gyv = w0[e] + 2.f * w0[e + 1] + w0[e + 2] - w2[e] - 2.f * w2[e + 1] - w2[e + 2];
        float m = sqrtf(gxv * gxv + gyv * gyv + 1e-8f);
        int gy = Y0 - 1 + r;
        int gx = X0 - 1 + c0 + e;
        res[e] = ((unsigned)gy < IMG_H && (unsigned)gx < IMG_W) ? m : 0.f;
      }
      float4* pd = (float4*)&s_mg[r * MW + c0];
      if (ch == 0) {
        *pd = make_float4(res[0], res[1], res[2], res[3]);
      } else {
        float4 s = *pd;
        s.x += res[0]; s.y += res[1]; s.z += res[2]; s.w += res[3];
        *pd = s;
      }
    }
    __syncthreads();
  }
  stageD(s_bs, s_mg, out, X0, Y0, tid);
}

__global__ __launch_bounds__(256, 7)
void canny_fused(const float* __restrict__ img,
                 const float* __restrict__ gauss,
                 float* __restrict__ out) {
  __shared__ float s_hb[HBH * HBW];   // 6400 B
  __shared__ float s_bl[BH * BW];     // 5760 B
  __shared__ float s_bs[SBH * SBW];   // 4896 B (Stage-D region only)
  __shared__ float s_mg[MH * MW];     // 4896 B -> total 21952 B, 7 blocks/CU

  const int tid = threadIdx.x;
  const int X0 = blockIdx.x * TW;
  const int Y0 = blockIdx.y * TH;
  const float g0 = gauss[0], g1 = gauss[1], g2 = gauss[2],
              g3 = gauss[3], g4 = gauss[4];

  const bool interior = (blockIdx.x >= 1) && (blockIdx.x <= 126) &&
                        (blockIdx.y >= 1) && (blockIdx.y <= 126);
  if (interior)
    pipeline_interior(img, g0, g1, g2, g3, g4, X0, Y0, tid, s_hb, s_bl, s_bs, s_mg, out);
  else
    pipeline_boundary(img, g0, g1, g2, g3, g4, X0, Y0, tid, s_hb, s_bl, s_bs, s_mg, out);
}

extern "C" void kernel_launch(void* const* d_in, const int* in_sizes, int n_in,
                              void* d_out, int out_size, void* d_ws, size_t ws_size,
                              hipStream_t stream) {
  const float* img   = (const float*)d_in[0];
  const float* gauss = (const float*)d_in[1];
  float* out = (float*)d_out;
  dim3 grid(IMG_W / TW, IMG_H / TH);
  canny_fused<<<grid, 256, 0, stream>>>(img, gauss, out);
}